// Round 1
// baseline (998.583 us; speedup 1.0000x reference)
//
#include <hip/hip_runtime.h>

// ControllableNCA step, fp32, 3-pass fused implementation.
// B=64, C=20, H=W=128. LIVING=3, ALIVE_TH=0.1, FIRE_RATE=0.5.
// ws layout: [0, 4MB) pre_life_mask (B*H*W floats); [4MB, 8MB) x_new living-channel plane.

#define BB 64
#define CC 20
#define HH 128
#define WW 128
#define LIVCH 3
#define TC 60      // 3*C perception channels
#define HID 128    // hidden width
#define NPIX (BB*HH*WW)

__global__ __launch_bounds__(256) void nca_pre_mask(const float* __restrict__ x,
                                                    float* __restrict__ mpre) {
    int idx = blockIdx.x * 256 + threadIdx.x;
    int w = idx & (WW - 1);
    int h = (idx >> 7) & (HH - 1);
    int b = idx >> 14;
    const float* ch = x + ((size_t)b * CC + LIVCH) * (HH * WW);
    float m = -1e30f;
    #pragma unroll
    for (int dy = -1; dy <= 1; ++dy) {
        int y = h + dy;
        if ((unsigned)y >= HH) continue;
        #pragma unroll
        for (int dx = -1; dx <= 1; ++dx) {
            int xx = w + dx;
            if ((unsigned)xx >= WW) continue;
            m = fmaxf(m, ch[y * WW + xx]);
        }
    }
    mpre[idx] = (m > 0.1f) ? 1.0f : 0.0f;
}

__global__ __launch_bounds__(256) void nca_main(const float* __restrict__ x,
                                                const float* __restrict__ goal,
                                                const float* __restrict__ rnd,
                                                const float* __restrict__ pw,
                                                const float* __restrict__ w1,
                                                const float* __restrict__ b1,
                                                const float* __restrict__ w2,
                                                const float* __restrict__ mpre,
                                                float* __restrict__ xnew,
                                                float* __restrict__ ch3out) {
    int idx = blockIdx.x * 256 + threadIdx.x;
    int w = idx & (WW - 1);
    int h = (idx >> 7) & (HH - 1);
    int b = idx >> 14;
    size_t base_b = (size_t)b * CC * (HH * WW);
    int pixoff = h * WW + w;

    // ---- depthwise 3x3 perception on xg = x + goal * pre_mask ----
    float p[TC];
    #pragma unroll
    for (int i = 0; i < TC; ++i) p[i] = 0.0f;

    #pragma unroll
    for (int dy = -1; dy <= 1; ++dy) {
        int y = h + dy;
        bool yok = (unsigned)y < HH;
        #pragma unroll
        for (int dx = -1; dx <= 1; ++dx) {
            int xx = w + dx;
            bool ok = yok && ((unsigned)xx < WW);
            int off = y * WW + xx;
            float m = ok ? mpre[b * (HH * WW) + off] : 0.0f;
            const int kidx = (dy + 1) * 3 + (dx + 1);
            #pragma unroll
            for (int c = 0; c < CC; ++c) {
                float v = 0.0f;
                if (ok) {
                    size_t o = base_b + (size_t)c * (HH * WW) + off;
                    v = x[o] + goal[o] * m;
                }
                #pragma unroll
                for (int k = 0; k < 3; ++k) {
                    // pw index is wave-uniform & compile-time -> scalar loads
                    p[3 * c + k] = fmaf(pw[(3 * c + k) * 9 + kidx], v, p[3 * c + k]);
                }
            }
        }
    }

    // ---- 1x1 dense: 60 -> 128 (ReLU) -> 20, weights via scalar path ----
    float acc[CC];
    #pragma unroll
    for (int o = 0; o < CC; ++o) acc[o] = 0.0f;

    #pragma unroll 2
    for (int j = 0; j < HID; ++j) {
        float hj = b1[j];
        #pragma unroll
        for (int c = 0; c < TC; ++c)
            hj = fmaf(w1[j * TC + c], p[c], hj);
        hj = fmaxf(hj, 0.0f);
        #pragma unroll
        for (int o = 0; o < CC; ++o)
            acc[o] = fmaf(w2[o * HID + j], hj, acc[o]);
    }

    // ---- stochastic update ----
    float rm = (rnd[b * (HH * WW) + pixoff] < 0.5f) ? 1.0f : 0.0f;
    #pragma unroll
    for (int c = 0; c < CC; ++c) {
        size_t o = base_b + (size_t)c * (HH * WW) + pixoff;
        float xn = x[o] + rm * acc[c];
        xnew[o] = xn;
        if (c == LIVCH) ch3out[b * (HH * WW) + pixoff] = xn;
    }
}

__global__ __launch_bounds__(256) void nca_finalize(const float* __restrict__ ch3,
                                                    const float* __restrict__ mpre,
                                                    float* __restrict__ xnew) {
    int idx = blockIdx.x * 256 + threadIdx.x;
    int w = idx & (WW - 1);
    int h = (idx >> 7) & (HH - 1);
    int b = idx >> 14;
    const float* plane = ch3 + b * (HH * WW);
    float m = -1e30f;
    #pragma unroll
    for (int dy = -1; dy <= 1; ++dy) {
        int y = h + dy;
        if ((unsigned)y >= HH) continue;
        #pragma unroll
        for (int dx = -1; dx <= 1; ++dx) {
            int xx = w + dx;
            if ((unsigned)xx >= WW) continue;
            m = fmaxf(m, plane[y * WW + xx]);
        }
    }
    bool post = m > 0.1f;
    bool pre = mpre[idx] > 0.5f;
    float life = (pre && post) ? 1.0f : 0.0f;

    size_t base_b = (size_t)b * CC * (HH * WW);
    int pixoff = h * WW + w;
    #pragma unroll
    for (int c = 0; c < CC; ++c) {
        size_t o = base_b + (size_t)c * (HH * WW) + pixoff;
        float v = xnew[o] * life;
        v = fminf(fmaxf(v, -10.0f), 10.0f);
        xnew[o] = v;
    }
}

extern "C" void kernel_launch(void* const* d_in, const int* in_sizes, int n_in,
                              void* d_out, int out_size, void* d_ws, size_t ws_size,
                              hipStream_t stream) {
    const float* x    = (const float*)d_in[0];
    const float* goal = (const float*)d_in[1];
    const float* rnd  = (const float*)d_in[2];
    const float* pw   = (const float*)d_in[3];
    const float* w1   = (const float*)d_in[4];
    const float* b1   = (const float*)d_in[5];
    const float* w2   = (const float*)d_in[6];
    float* out = (float*)d_out;

    float* mpre = (float*)d_ws;              // NPIX floats
    float* ch3  = mpre + NPIX;               // NPIX floats

    dim3 blk(256), grd(NPIX / 256);
    hipLaunchKernelGGL(nca_pre_mask, grd, blk, 0, stream, x, mpre);
    hipLaunchKernelGGL(nca_main, grd, blk, 0, stream,
                       x, goal, rnd, pw, w1, b1, w2, mpre, out, ch3);
    hipLaunchKernelGGL(nca_finalize, grd, blk, 0, stream, ch3, mpre, out);
}

// Round 5
// 443.688 us; speedup vs baseline: 2.2506x; 2.2506x over previous
//
#include <hip/hip_runtime.h>
#include <hip/hip_bf16.h>

// ControllableNCA step. B=64, C=20, H=W=128. LIVING=3, ALIVE_TH=0.1, FIRE_RATE=0.5.
// Pass 1: pre-alive mask.
// Pass 2: conv(fp32) -> GEMM1 split-bf16 (fp32-grade h) -> ch3 update fp32 on VALU
//         (alive-mask channel must be fp32-exact: threshold discontinuity!),
//         other channels via single-bf16 GEMM2. Writes unclipped x_new + ch3 plane.
// Pass 3: post-alive + life mask + clip.

#define BB 64
#define CC 20
#define HH 128
#define WW 128
#define LIVCH 3
#define NPIX (BB*HH*WW)

typedef __attribute__((ext_vector_type(8))) short short8;
typedef __attribute__((ext_vector_type(4))) float f32x4;

#define LDS_FENCE() asm volatile("" ::: "memory")

static __device__ __forceinline__ unsigned short f2bf(float f) {
    __hip_bfloat16 h = __float2bfloat16(f);   // RNE
    return *reinterpret_cast<unsigned short*>(&h);
}
static __device__ __forceinline__ float bf2f(unsigned short u) {
    unsigned int v = ((unsigned int)u) << 16;
    union { unsigned int i; float f; } c; c.i = v; return c.f;
}

__global__ __launch_bounds__(256) void nca_pre_mask(const float* __restrict__ x,
                                                    float* __restrict__ mpre) {
    int idx = blockIdx.x * 256 + threadIdx.x;
    int w = idx & (WW - 1);
    int h = (idx >> 7) & (HH - 1);
    int b = idx >> 14;
    const float* ch = x + ((size_t)b * CC + LIVCH) * (HH * WW);
    float m = -1e30f;
    #pragma unroll
    for (int dy = -1; dy <= 1; ++dy) {
        int y = h + dy;
        if ((unsigned)y >= HH) continue;
        #pragma unroll
        for (int dx = -1; dx <= 1; ++dx) {
            int xx = w + dx;
            if ((unsigned)xx >= WW) continue;
            m = fmaxf(m, ch[y * WW + xx]);
        }
    }
    mpre[idx] = (m > 0.1f) ? 1.0f : 0.0f;
}

// Block: 256 threads = 4 waves; 256 pixels = 2 image rows. Grid = 64*64 = 4096.
__global__ __launch_bounds__(256, 2) void nca_main_mfma(
    const float* __restrict__ x, const float* __restrict__ goal,
    const float* __restrict__ rnd, const float* __restrict__ pw,
    const float* __restrict__ w1, const float* __restrict__ b1,
    const float* __restrict__ w2, const float* __restrict__ mpre,
    float* __restrict__ xnew, float* __restrict__ ch3out) {

    // Padded strides: all b128 rows 16B-aligned; <=2-way bank conflicts.
    __shared__ float          p_st[4][16 * 68];   // per-wave p tile, fp32   (17408 B)
    __shared__ unsigned short w1h[128 * 72];      // w1 hi bf16              (18432 B)
    __shared__ unsigned short w1l[128 * 72];      // w1 lo bf16              (18432 B)
    __shared__ unsigned short w2s[24 * 136];      // w2 single bf16, rows 20..23 zero (6528 B)
    __shared__ unsigned short h_st[4][16 * 136];  // per-wave h bf16         (17408 B)
    __shared__ float edge_lds[4 * 2 * 20];        // xg at cols 63,64        (640 B)

    const int tid  = threadIdx.x;
    const int lane = tid & 63;
    const int wv   = tid >> 6;
    const int blk  = blockIdx.x;
    const int b    = blk >> 6;
    const int y0   = (blk & 63) * 2;

    // ---- stage w1 hi/lo split (Dekker: v = hi + lo + O(2^-17 v)) ----
    for (int i = tid; i < 128 * 64; i += 256) {
        int n = i >> 6, k = i & 63;
        float v = (k < 60) ? w1[n * 60 + k] : 0.0f;
        unsigned short hi = f2bf(v);
        w1h[n * 72 + k] = hi;
        w1l[n * 72 + k] = f2bf(v - bf2f(hi));
    }
    // ---- stage w2 single bf16, rows 20..23 zero ----
    for (int i = tid; i < 24 * 128; i += 256) {
        int n = i >> 7, k = i & 127;
        float v = (n < 20) ? w2[n * 128 + k] : 0.0f;
        w2s[n * 136 + k] = f2bf(v);
    }
    // ---- stage cross-wave edge xg values (cols 63 & 64, 4 rows, 20 ch) ----
    if (tid < 160) {
        int side = tid & 1, r = (tid >> 1) & 3, c = tid >> 3;
        int y = y0 - 1 + r, col = 63 + side;
        float v = 0.0f;
        if (y >= 0 && y < HH) {
            int gi = ((b * CC + c) << 14) + (y << 7) + col;
            float m = mpre[(b << 14) + (y << 7) + col];
            v = __builtin_fmaf(goal[gi], m, x[gi]);
        }
        edge_lds[(r * 2 + side) * 20 + c] = v;
    }
    __syncthreads();   // edge/w1/w2 staging visible to all waves

    // ---- depthwise 3x3 conv on xg, per-lane pixel, fp32 ----
    const int y    = y0 + (tid >> 7);
    const int wcol = tid & 127;
    float p[64];
    #pragma unroll
    for (int i = 0; i < 64; ++i) p[i] = 0.0f;

    #pragma unroll
    for (int dy = -1; dy <= 1; ++dy) {
        int yy = y + dy;
        if (yy >= 0 && yy < HH) {              // wave-uniform
            int rr = dy + 1 + (tid >> 7);
            float mp = mpre[(b << 14) + (yy << 7) + wcol];
            #pragma unroll
            for (int c = 0; c < CC; ++c) {
                int gi = ((b * CC + c) << 14) + (yy << 7) + wcol;
                float v  = __builtin_fmaf(goal[gi], mp, x[gi]);
                float vm = __shfl_up(v, 1);
                float vp = __shfl_down(v, 1);
                if (lane == 0)  vm = (wcol == 0)   ? 0.0f : edge_lds[(rr * 2 + 0) * 20 + c];
                if (lane == 63) vp = (wcol == 127) ? 0.0f : edge_lds[(rr * 2 + 1) * 20 + c];
                #pragma unroll
                for (int kk = 0; kk < 3; ++kk) {
                    const int t = 3 * c + kk;
                    const float* pr = pw + t * 9 + (dy + 1) * 3;
                    p[t] = __builtin_fmaf(pr[0], vm, p[t]);
                    p[t] = __builtin_fmaf(pr[1], v,  p[t]);
                    p[t] = __builtin_fmaf(pr[2], vp, p[t]);
                }
            }
        }
    }

    const int l15 = lane & 15;
    const int l4  = lane >> 4;

    // per-lane fp32 constants from GLOBAL (exactness for mask path)
    float bias_[8], w2r3[8];
    #pragma unroll
    for (int nt = 0; nt < 8; ++nt) {
        bias_[nt] = b1[nt * 16 + l15];
        w2r3[nt]  = w2[3 * 128 + nt * 16 + l15];
    }
    short8 b2f[2][4];
    #pragma unroll
    for (int nt = 0; nt < 2; ++nt) {
        int nc = nt * 16 + l15; if (nc > 23) nc = 23;   // rows 20..23 are zeros
        #pragma unroll
        for (int ks = 0; ks < 4; ++ks)
            b2f[nt][ks] = *reinterpret_cast<const short8*>(w2s + nc * 136 + ks * 32 + l4 * 8);
    }

    float* pwv = &p_st[wv][0];
    unsigned short* hwv = &h_st[wv][0];
    const int hwbase = ((blk & 63) << 8) + (wv << 6);

    for (int mt = 0; mt < 4; ++mt) {
        // ---- stage this tile's p rows (wave-local; lanes [mt*16, mt*16+16)) ----
        LDS_FENCE();   // WAR vs prior tile's A-frag reads
        if ((lane >> 4) == mt) {
            const int row = l15;
            #pragma unroll
            for (int g = 0; g < 16; ++g) {
                f32x4 t = { p[g*4+0], p[g*4+1], p[g*4+2], p[g*4+3] };
                *reinterpret_cast<f32x4*>(pwv + row * 68 + g * 4) = t;
            }
        }
        LDS_FENCE();
        // ---- A fragments, hi/lo split in-register ----
        short8 ah[2], al[2];
        #pragma unroll
        for (int ks = 0; ks < 2; ++ks) {
            f32x4 u0 = *reinterpret_cast<const f32x4*>(pwv + l15 * 68 + ks * 32 + l4 * 8);
            f32x4 u1 = *reinterpret_cast<const f32x4*>(pwv + l15 * 68 + ks * 32 + l4 * 8 + 4);
            #pragma unroll
            for (int j = 0; j < 4; ++j) {
                unsigned short h0 = f2bf(u0[j]);
                ah[ks][j]     = (short)h0;
                al[ks][j]     = (short)f2bf(u0[j] - bf2f(h0));
                unsigned short h1 = f2bf(u1[j]);
                ah[ks][4 + j] = (short)h1;
                al[ks][4 + j] = (short)f2bf(u1[j] - bf2f(h1));
            }
        }
        // ---- GEMM1, 4-term split: fp32-grade h ----
        f32x4 C1[8];
        #pragma unroll
        for (int nt = 0; nt < 8; ++nt) {
            f32x4 c = { bias_[nt], bias_[nt], bias_[nt], bias_[nt] };
            #pragma unroll
            for (int ks = 0; ks < 2; ++ks) {
                const short8 bh = *reinterpret_cast<const short8*>(
                    w1h + (nt * 16 + l15) * 72 + ks * 32 + l4 * 8);
                const short8 bl = *reinterpret_cast<const short8*>(
                    w1l + (nt * 16 + l15) * 72 + ks * 32 + l4 * 8);
                c = __builtin_amdgcn_mfma_f32_16x16x32_bf16(ah[ks], bh, c, 0, 0, 0);
                c = __builtin_amdgcn_mfma_f32_16x16x32_bf16(al[ks], bh, c, 0, 0, 0);
                c = __builtin_amdgcn_mfma_f32_16x16x32_bf16(ah[ks], bl, c, 0, 0, 0);
                c = __builtin_amdgcn_mfma_f32_16x16x32_bf16(al[ks], bl, c, 0, 0, 0);
            }
            C1[nt] = c;
        }
        // ---- relu; ch3 update in fp32 (mask-exact); stage h bf16 ----
        float s[4] = {0.f, 0.f, 0.f, 0.f};
        LDS_FENCE();   // WAR vs prior tile's GEMM2 reads
        #pragma unroll
        for (int nt = 0; nt < 8; ++nt) {
            #pragma unroll
            for (int r = 0; r < 4; ++r) {
                float hv = fmaxf(C1[nt][r], 0.0f);
                s[r] = __builtin_fmaf(w2r3[nt], hv, s[r]);
                hwv[(l4 * 4 + r) * 136 + nt * 16 + l15] = f2bf(hv);
            }
        }
        LDS_FENCE();
        // reduce s over the 16-lane l15 group (lane bits 0..3)
        #pragma unroll
        for (int r = 0; r < 4; ++r) {
            s[r] += __shfl_xor(s[r], 1, 64);
            s[r] += __shfl_xor(s[r], 2, 64);
            s[r] += __shfl_xor(s[r], 4, 64);
            s[r] += __shfl_xor(s[r], 8, 64);
        }
        // ---- GEMM2 single-bf16 (values only; ch3 overridden below) ----
        f32x4 C2[2];
        C2[0] = (f32x4){0.f, 0.f, 0.f, 0.f};
        C2[1] = (f32x4){0.f, 0.f, 0.f, 0.f};
        #pragma unroll
        for (int ks = 0; ks < 4; ++ks) {
            short8 a2 = *reinterpret_cast<const short8*>(hwv + l15 * 136 + ks * 32 + l4 * 8);
            C2[0] = __builtin_amdgcn_mfma_f32_16x16x32_bf16(a2, b2f[0][ks], C2[0], 0, 0, 0);
            C2[1] = __builtin_amdgcn_mfma_f32_16x16x32_bf16(a2, b2f[1][ks], C2[1], 0, 0, 0);
        }
        // ---- epilogue: x_new = x + rand_mask * out ----
        const int hw = hwbase + (mt << 4) + (l4 << 2);
        float4 r4 = *reinterpret_cast<const float4*>(rnd + (b << 14) + hw);
        float rm0 = (r4.x < 0.5f) ? 1.0f : 0.0f;
        float rm1 = (r4.y < 0.5f) ? 1.0f : 0.0f;
        float rm2 = (r4.z < 0.5f) ? 1.0f : 0.0f;
        float rm3 = (r4.w < 0.5f) ? 1.0f : 0.0f;
        #pragma unroll
        for (int nt = 0; nt < 2; ++nt) {
            int o = (nt << 4) + l15;
            if (o < CC) {
                const bool isliv = (nt == 0) && (l15 == LIVCH);
                float u0 = isliv ? s[0] : C2[nt][0];
                float u1 = isliv ? s[1] : C2[nt][1];
                float u2 = isliv ? s[2] : C2[nt][2];
                float u3 = isliv ? s[3] : C2[nt][3];
                int gi = ((b * CC + o) << 14) + hw;
                float4 xo = *reinterpret_cast<const float4*>(x + gi);
                float4 vo;
                vo.x = __builtin_fmaf(rm0, u0, xo.x);
                vo.y = __builtin_fmaf(rm1, u1, xo.y);
                vo.z = __builtin_fmaf(rm2, u2, xo.z);
                vo.w = __builtin_fmaf(rm3, u3, xo.w);
                *reinterpret_cast<float4*>(xnew + gi) = vo;
                if (isliv)
                    *reinterpret_cast<float4*>(ch3out + (b << 14) + hw) = vo;
            }
        }
    }
}

__global__ __launch_bounds__(256) void nca_finalize(const float* __restrict__ ch3,
                                                    const float* __restrict__ mpre,
                                                    float* __restrict__ xnew) {
    int idx = blockIdx.x * 256 + threadIdx.x;
    int w = idx & (WW - 1);
    int h = (idx >> 7) & (HH - 1);
    int b = idx >> 14;
    const float* plane = ch3 + b * (HH * WW);
    float m = -1e30f;
    #pragma unroll
    for (int dy = -1; dy <= 1; ++dy) {
        int y = h + dy;
        if ((unsigned)y >= HH) continue;
        #pragma unroll
        for (int dx = -1; dx <= 1; ++dx) {
            int xx = w + dx;
            if ((unsigned)xx >= WW) continue;
            m = fmaxf(m, plane[y * WW + xx]);
        }
    }
    bool post = m > 0.1f;
    bool pre = mpre[idx] > 0.5f;
    float life = (pre && post) ? 1.0f : 0.0f;

    size_t base_b = (size_t)b * CC * (HH * WW);
    int pixoff = h * WW + w;
    #pragma unroll
    for (int c = 0; c < CC; ++c) {
        size_t o = base_b + (size_t)c * (HH * WW) + pixoff;
        float v = xnew[o] * life;
        v = fminf(fmaxf(v, -10.0f), 10.0f);
        xnew[o] = v;
    }
}

extern "C" void kernel_launch(void* const* d_in, const int* in_sizes, int n_in,
                              void* d_out, int out_size, void* d_ws, size_t ws_size,
                              hipStream_t stream) {
    const float* x    = (const float*)d_in[0];
    const float* goal = (const float*)d_in[1];
    const float* rnd  = (const float*)d_in[2];
    const float* pw   = (const float*)d_in[3];
    const float* w1   = (const float*)d_in[4];
    const float* b1   = (const float*)d_in[5];
    const float* w2   = (const float*)d_in[6];
    float* out = (float*)d_out;

    float* mpre = (float*)d_ws;              // NPIX floats
    float* ch3  = mpre + NPIX;               // NPIX floats

    dim3 blk(256), grd(NPIX / 256);
    hipLaunchKernelGGL(nca_pre_mask, grd, blk, 0, stream, x, mpre);
    hipLaunchKernelGGL(nca_main_mfma, dim3(BB * HH / 2), blk, 0, stream,
                       x, goal, rnd, pw, w1, b1, w2, mpre, out, ch3);
    hipLaunchKernelGGL(nca_finalize, grd, blk, 0, stream, ch3, mpre, out);
}